// Round 2
// baseline (559.283 us; speedup 1.0000x reference)
//
#include <hip/hip_runtime.h>
#include <hip/hip_bf16.h>
#include <stdint.h>

// ResNetV1 sparse conv block, MI355X (gfx950).
// out = relu( conv(relu(conv(x,W0)), W1) + x ),  conv[n,d] = sum_k sum_c x[idx[n,k],c] * W[k,c,d]
// N=150000, K=27, C=64.
// R2: software-pipelined k-loop. A-gather prefetched into regs (idx prefetched 2 ahead),
// double-buffered LDS A tile, ONE barrier per k. B tile lives in registers, loaded direct
// from global (L2-hot packed W), prefetched 1 ahead. Global loads stay in flight across the
// barrier (they target regs, so the barrier only drains lgkmcnt).

typedef __attribute__((ext_vector_type(8))) short short8;
typedef __attribute__((ext_vector_type(4))) float f32x4;

#define NV 150000
#define KOFF 27
#define MT 128

static __device__ __forceinline__ ushort f2bf(float f) {
  union { float f; uint32_t u; } v; v.f = f;
  uint32_t u = v.u;
  return (ushort)((u + 0x7fffu + ((u >> 16) & 1u)) >> 16);
}

__global__ void cvt_x_kernel(const float* __restrict__ x, ushort* __restrict__ xb, int n) {
  int i = blockIdx.x * 256 + threadIdx.x;
  if (i * 4 >= n) return;
  float4 v = ((const float4*)x)[i];
  ushort4 o;
  o.x = f2bf(v.x); o.y = f2bf(v.y); o.z = f2bf(v.z); o.w = f2bf(v.w);
  ((ushort4*)xb)[i] = o;
}

// Pack W [27][64][64] fp32 -> bf16 B-fragment order:
// flat = (((k*2+s)*4+ct)*64 + lane)*8 + j  <-  W[k][c=s*32+(lane>>4)*8+j][d=ct*16+(lane&15)]
__global__ void pack_w_kernel(const float* __restrict__ W, ushort* __restrict__ wp, int total) {
  int o = blockIdx.x * 256 + threadIdx.x;
  if (o >= total) return;
  int j  = o & 7;
  int l  = (o >> 3) & 63;
  int ct = (o >> 9) & 3;
  int s  = (o >> 11) & 1;
  int k  = o >> 12;
  int c  = s * 32 + (l >> 4) * 8 + j;
  int d  = ct * 16 + (l & 15);
  wp[o] = f2bf(W[(k * 64 + c) * 64 + d]);
}

// MODE 0: y = relu(conv(feat,W)) -> bf16 out_bf
// MODE 1: y = relu(conv(feat,W) + resid) -> fp32 out_f
template <int MODE>
__global__ __launch_bounds__(256) void conv_kernel(
    const ushort* __restrict__ feat,   // [N,64] bf16 bits
    const int*    __restrict__ nbr,    // [N,27]
    const ushort* __restrict__ wp,     // packed W, 27*4096 bf16
    const float*  __restrict__ resid,  // [N,64] fp32 (MODE 1)
    ushort*       __restrict__ out_bf, // MODE 0
    float*        __restrict__ out_f,  // MODE 1
    int n) {
  __shared__ __align__(16) ushort sA[2][MT * 64];  // 2 x 16 KB, XOR-swizzled 16B chunks
  __shared__ int sIdx[MT * KOFF];                  // 13.5 KB

  const int tid  = threadIdx.x;
  const int m0   = blockIdx.x * MT;
  const int wave = tid >> 6;
  const int lane = tid & 63;
  const int quad = lane >> 4;
  const int lo   = lane & 15;

  // Gather-staging geometry: thread handles rows r0+32*i (i=0..3), 16B segment seg.
  const int seg    = tid & 7;
  const int r0     = tid >> 3;            // 0..31
  const int chunkW = seg ^ (r0 & 7);      // write chunk, same for all 4 rows

  // Stage neighbor indices (contiguous global read).
  {
    const int cnt  = (n - m0) >= MT ? MT * KOFF : (n - m0) * KOFF;
    const int base = m0 * KOFF;
    #pragma unroll
    for (int u = tid; u < MT * KOFF; u += 256)
      sIdx[u] = (u < cnt) ? nbr[base + u] : 0;
  }

  f32x4 acc[2][4];
  #pragma unroll
  for (int rt = 0; rt < 2; ++rt)
    #pragma unroll
    for (int ct = 0; ct < 4; ++ct)
      acc[rt][ct] = (f32x4)0.0f;

  __syncthreads();

  const short8* wv = (const short8*)wp;  // [k*512 + t*64 + lane]

  // Pipeline primers: A-gather regs for k=0, B regs for k=0, indices for k=1.
  float4 av[4];
  short8 bn[8];
  int gi2[4];
  #pragma unroll
  for (int i = 0; i < 4; ++i) {
    int g = sIdx[(r0 + 32 * i) * KOFF + 0];
    av[i] = ((const float4*)(feat + g * 64))[seg];
  }
  #pragma unroll
  for (int t = 0; t < 8; ++t) bn[t] = wv[t * 64 + lane];
  #pragma unroll
  for (int i = 0; i < 4; ++i) gi2[i] = sIdx[(r0 + 32 * i) * KOFF + 1];

  for (int k = 0; k < KOFF; ++k) {
    const int buf = k & 1;

    // Commit prefetched A tile to LDS (waits vmcnt on last iter's gathers).
    float4* sW = (float4*)sA[buf];
    #pragma unroll
    for (int i = 0; i < 4; ++i)
      sW[(r0 + 32 * i) * 8 + chunkW] = av[i];

    // Keep current B, then issue next iteration's loads (stay in flight past barrier).
    short8 bc[8];
    #pragma unroll
    for (int t = 0; t < 8; ++t) bc[t] = bn[t];

    if (k + 1 < KOFF) {
      #pragma unroll
      for (int i = 0; i < 4; ++i)
        av[i] = ((const float4*)(feat + gi2[i] * 64))[seg];
      const short8* wk = wv + (k + 1) * 512;
      #pragma unroll
      for (int t = 0; t < 8; ++t) bn[t] = wk[t * 64 + lane];
      if (k + 2 < KOFF) {
        #pragma unroll
        for (int i = 0; i < 4; ++i) gi2[i] = sIdx[(r0 + 32 * i) * KOFF + (k + 2)];
      }
    }

    __syncthreads();  // A[buf] visible; only lgkmcnt drained, gathers still in flight

    const short8* sR = (const short8*)sA[buf];
    #pragma unroll
    for (int s = 0; s < 2; ++s) {
      #pragma unroll
      for (int rt = 0; rt < 2; ++rt) {
        int row   = wave * 32 + rt * 16 + lo;
        int chunk = (s * 4 + quad) ^ (row & 7);
        short8 a  = sR[row * 8 + chunk];
        #pragma unroll
        for (int ct = 0; ct < 4; ++ct)
          acc[rt][ct] = __builtin_amdgcn_mfma_f32_16x16x32_bf16(a, bc[s * 4 + ct], acc[rt][ct], 0, 0, 0);
      }
    }
    // No trailing barrier: next iter writes the other buffer; the single barrier
    // per iteration orders reuse of this buffer two iterations out.
  }

  // Epilogue. acc[rt][ct][j] -> out[m0 + wave*32 + rt*16 + quad*4 + j][ct*16 + lo]
  #pragma unroll
  for (int rt = 0; rt < 2; ++rt) {
    int rbase = m0 + wave * 32 + rt * 16 + quad * 4;
    #pragma unroll
    for (int ct = 0; ct < 4; ++ct) {
      int col = ct * 16 + lo;
      #pragma unroll
      for (int j = 0; j < 4; ++j) {
        int r = rbase + j;
        if (r < n) {
          float v = acc[rt][ct][j];
          if (MODE == 0) {
            v = v > 0.0f ? v : 0.0f;
            out_bf[r * 64 + col] = f2bf(v);
          } else {
            v += resid[r * 64 + col];
            v = v > 0.0f ? v : 0.0f;
            out_f[r * 64 + col] = v;
          }
        }
      }
    }
  }
}

extern "C" void kernel_launch(void* const* d_in, const int* in_sizes, int n_in,
                              void* d_out, int out_size, void* d_ws, size_t ws_size,
                              hipStream_t stream) {
  const float* x   = (const float*)d_in[0];
  const int*   nbr = (const int*)d_in[1];
  const float* W0  = (const float*)d_in[2];
  const float* W1  = (const float*)d_in[3];
  float* out = (float*)d_out;

  const int n    = NV;
  const int nc   = NV * 64;        // 9,600,000
  const int wtot = KOFF * 4096;    // 110,592

  ushort* xb  = (ushort*)d_ws;
  ushort* yb  = xb + nc;
  ushort* wp0 = yb + nc;
  ushort* wp1 = wp0 + wtot;

  cvt_x_kernel<<<(nc / 4 + 255) / 256, 256, 0, stream>>>(x, xb, nc);
  pack_w_kernel<<<(wtot + 255) / 256, 256, 0, stream>>>(W0, wp0, wtot);
  pack_w_kernel<<<(wtot + 255) / 256, 256, 0, stream>>>(W1, wp1, wtot);

  const int grid = (n + MT - 1) / MT;  // 1172
  conv_kernel<0><<<grid, 256, 0, stream>>>(xb, nbr, wp0, nullptr, yb, nullptr, n);
  conv_kernel<1><<<grid, 256, 0, stream>>>(yb, nbr, wp1, x, nullptr, out, n);
}

// Round 3
// 327.018 us; speedup vs baseline: 1.7103x; 1.7103x over previous
//
#include <hip/hip_runtime.h>
#include <hip/hip_bf16.h>
#include <stdint.h>

// ResNetV1 sparse conv block, MI355X (gfx950).
// out = relu( conv(relu(conv(x,W0)), W1) + x ),  conv[n,d] = sum_k sum_c x[idx[n,k],c] * W[k,c,d]
// N=150000, K=27, C=64.
// R3: barrier-free, LDS-free conv. Key insight: the old LDS A-tile had zero cross-wave
// reuse (each wave consumed only its own rows) -- so gather A fragments DIRECTLY into
// registers. One wave per 64 rows (4 x 16-row MFMA tiles), 64-thread blocks for load
// balance. B fragments loaded per-k from packed W (216 KB total, L2-hot). No barriers,
// no LDS: waves free-run, maximizing outstanding gathers (R1 was latency-bound at
// 1.5 TB/s). VGPR ~145, capped 168 via __launch_bounds__(64,3) -- no spills (R2 lesson:
// spills showed as +270 MB WRITE_SIZE).

typedef __attribute__((ext_vector_type(8))) short short8;
typedef __attribute__((ext_vector_type(4))) float f32x4;

#define NV 150000
#define KOFF 27

static __device__ __forceinline__ ushort f2bf(float f) {
  union { float f; uint32_t u; } v; v.f = f;
  uint32_t u = v.u;
  return (ushort)((u + 0x7fffu + ((u >> 16) & 1u)) >> 16);
}

__global__ void cvt_x_kernel(const float* __restrict__ x, ushort* __restrict__ xb, int n) {
  int i = blockIdx.x * 256 + threadIdx.x;
  if (i * 4 >= n) return;
  float4 v = ((const float4*)x)[i];
  ushort4 o;
  o.x = f2bf(v.x); o.y = f2bf(v.y); o.z = f2bf(v.z); o.w = f2bf(v.w);
  ((ushort4*)xb)[i] = o;
}

// Pack W [27][64][64] fp32 -> bf16 B-fragment order:
// flat = (((k*2+s)*4+ct)*64 + lane)*8 + j  <-  W[k][c=s*32+(lane>>4)*8+j][d=ct*16+(lane&15)]
__global__ void pack_w_kernel(const float* __restrict__ W, ushort* __restrict__ wp, int total) {
  int o = blockIdx.x * 256 + threadIdx.x;
  if (o >= total) return;
  int j  = o & 7;
  int l  = (o >> 3) & 63;
  int ct = (o >> 9) & 3;
  int s  = (o >> 11) & 1;
  int k  = o >> 12;
  int c  = s * 32 + (l >> 4) * 8 + j;
  int d  = ct * 16 + (l & 15);
  wp[o] = f2bf(W[(k * 64 + c) * 64 + d]);
}

// One wave (64 threads) per 64 rows. MODE 0: relu(conv) -> bf16. MODE 1: relu(conv+resid) -> fp32.
template <int MODE>
__global__ __launch_bounds__(64, 3) void conv_kernel(
    const ushort* __restrict__ feat,   // [N,64] bf16 bits
    const int*    __restrict__ nbr,    // [N,27]
    const ushort* __restrict__ wp,     // packed W, 27*4096 bf16
    const float*  __restrict__ resid,  // [N,64] fp32 (MODE 1)
    ushort*       __restrict__ out_bf, // MODE 0
    float*        __restrict__ out_f,  // MODE 1
    int n) {
  const int lane = threadIdx.x;       // 0..63
  const int quad = lane >> 4;
  const int lo   = lane & 15;
  const int mw   = blockIdx.x * 64;   // first row of this wave

  // Per-lane neighbor-list offsets for the 4 row-tiles (clamped for tail rows).
  int roff[4];
  #pragma unroll
  for (int rt = 0; rt < 4; ++rt) {
    int r = mw + rt * 16 + lo;
    r = r < n ? r : n - 1;
    roff[rt] = r * KOFF;
  }

  const short8* wv = (const short8*)wp;  // b frag t for offset k: wv[k*512 + t*64 + lane]

  f32x4 acc[4][4];
  #pragma unroll
  for (int rt = 0; rt < 4; ++rt)
    #pragma unroll
    for (int ct = 0; ct < 4; ++ct)
      acc[rt][ct] = (f32x4)0.0f;

  int gi[4];
  #pragma unroll
  for (int rt = 0; rt < 4; ++rt) gi[rt] = nbr[roff[rt]];

  #pragma unroll 1
  for (int k = 0; k < KOFF; ++k) {
    // Gather A fragments for current k: lane reads 2x16B from row gi[rt],
    // cols quad*8 and 32+quad*8. Random rows -> long latency; issue first.
    short8 a[4][2];
    #pragma unroll
    for (int rt = 0; rt < 4; ++rt) {
      const ushort* rowp = feat + gi[rt] * 64 + quad * 8;
      a[rt][0] = *(const short8*)(rowp);
      a[rt][1] = *(const short8*)(rowp + 32);
    }
    // Prefetch neighbor indices for k+1 (covers idx->gather dependence).
    if (k + 1 < KOFF) {
      #pragma unroll
      for (int rt = 0; rt < 4; ++rt) gi[rt] = nbr[roff[rt] + k + 1];
    }
    // B fragments for this k (1 KB/instr coalesced, L2-hot).
    short8 b[8];
    #pragma unroll
    for (int t = 0; t < 8; ++t) b[t] = wv[k * 512 + t * 64 + lane];
    // 32 MFMAs.
    #pragma unroll
    for (int s = 0; s < 2; ++s)
      #pragma unroll
      for (int rt = 0; rt < 4; ++rt)
        #pragma unroll
        for (int ct = 0; ct < 4; ++ct)
          acc[rt][ct] = __builtin_amdgcn_mfma_f32_16x16x32_bf16(a[rt][s], b[s * 4 + ct], acc[rt][ct], 0, 0, 0);
  }

  // Epilogue: acc[rt][ct][j] -> out[mw + rt*16 + quad*4 + j][ct*16 + lo]
  #pragma unroll
  for (int rt = 0; rt < 4; ++rt) {
    int rbase = mw + rt * 16 + quad * 4;
    #pragma unroll
    for (int ct = 0; ct < 4; ++ct) {
      int col = ct * 16 + lo;
      #pragma unroll
      for (int j = 0; j < 4; ++j) {
        int r = rbase + j;
        if (r < n) {
          float v = acc[rt][ct][j];
          if (MODE == 0) {
            v = v > 0.0f ? v : 0.0f;
            out_bf[r * 64 + col] = f2bf(v);
          } else {
            v += resid[r * 64 + col];
            v = v > 0.0f ? v : 0.0f;
            out_f[r * 64 + col] = v;
          }
        }
      }
    }
  }
}

extern "C" void kernel_launch(void* const* d_in, const int* in_sizes, int n_in,
                              void* d_out, int out_size, void* d_ws, size_t ws_size,
                              hipStream_t stream) {
  const float* x   = (const float*)d_in[0];
  const int*   nbr = (const int*)d_in[1];
  const float* W0  = (const float*)d_in[2];
  const float* W1  = (const float*)d_in[3];
  float* out = (float*)d_out;

  const int n    = NV;
  const int nc   = NV * 64;        // 9,600,000
  const int wtot = KOFF * 4096;    // 110,592

  ushort* xb  = (ushort*)d_ws;
  ushort* yb  = xb + nc;
  ushort* wp0 = yb + nc;
  ushort* wp1 = wp0 + wtot;

  cvt_x_kernel<<<(nc / 4 + 255) / 256, 256, 0, stream>>>(x, xb, nc);
  pack_w_kernel<<<(wtot + 255) / 256, 256, 0, stream>>>(W0, wp0, wtot);
  pack_w_kernel<<<(wtot + 255) / 256, 256, 0, stream>>>(W1, wp1, wtot);

  const int grid = (n + 63) / 64;  // 2344 one-wave blocks
  conv_kernel<0><<<grid, 64, 0, stream>>>(xb, nbr, wp0, nullptr, yb, nullptr, n);
  conv_kernel<1><<<grid, 64, 0, stream>>>(yb, nbr, wp1, x, nullptr, out, n);
}